// Round 8
// baseline (754.418 us; speedup 1.0000x reference)
//
#include <hip/hip_runtime.h>
#include <hip/hip_bf16.h>

#define BT_ 8192   // B*T
#define D_  512
#define V_  8192
#define NT2 32     // V / 256 col-tiles

// ---- INSTRUMENTATION (this round): solve K-loop/epilogue split exactly ----
#define GREPS 3    // gemm8 internal K-loop reps; with r6's 8K+E=1102: K=(1102-dur)/5

// d_out float offsets (outputs concatenated in return order)
#define OFF_Q      0
#define OFF_TOK    4194304
#define OFF_LOSS   4202496
#define OFF_SOFT   4202497
#define OFF_LOGITS 71311361
#define STAGE_F    4202500   // bf16 staging scratch inside soft region (16B-aligned)

#define TAU  0.02f

typedef __attribute__((ext_vector_type(8))) short bf16x8;
typedef __attribute__((ext_vector_type(4))) float f32x4;
typedef __attribute__((ext_vector_type(4))) unsigned short u16x4;

__device__ __forceinline__ unsigned short bf16rne(float f) {
  unsigned int u = __float_as_uint(f);
  return (unsigned short)((u + 0x7fffu + ((u >> 16) & 1u)) >> 16);
}

// ---------------- pass 0: fp32 -> bf16 for X and W (block-uniform source) ----------------
__global__ __launch_bounds__(256) void to_bf16_k(const f32x4* __restrict__ x,
                                                 const f32x4* __restrict__ w,
                                                 u16x4* __restrict__ xa,
                                                 u16x4* __restrict__ wb) {
  const int n4 = (BT_ * D_) / 4;
  const int half = gridDim.x >> 1;
  const bool isw = blockIdx.x >= half;
  const f32x4* __restrict__ s = isw ? w : x;
  u16x4* __restrict__ d = isw ? wb : xa;
  const int b0 = isw ? blockIdx.x - half : blockIdx.x;
  for (int i = b0 * 256 + threadIdx.x; i < n4; i += half * 256) {
    const f32x4 v = s[i];          // plain load: x/w re-read by rescue/finalize
    u16x4 o;
    o[0] = bf16rne(v[0]); o[1] = bf16rne(v[1]);
    o[2] = bf16rne(v[2]); o[3] = bf16rne(v[3]);
    d[i] = o;
  }
}

// ---------------- pass 1: 256x256 8-phase bf16 MFMA GEMM + fused stats epilogue ----------------
__device__ __forceinline__ void gload_lds16(const void* g, void* l) {
  __builtin_amdgcn_global_load_lds((const __attribute__((address_space(1))) void*)g,
                                   (__attribute__((address_space(3))) void*)l,
                                   16, 0, 0);
}

// raw barrier + compiler memory fence (no vmcnt/lgkm drain)
__device__ __forceinline__ void barf() {
  __builtin_amdgcn_s_barrier();
  asm volatile("" ::: "memory");
}
__device__ __forceinline__ void vmcnt2() { asm volatile("s_waitcnt vmcnt(2)" ::: "memory"); }
__device__ __forceinline__ void vmcnt0() { asm volatile("s_waitcnt vmcnt(0)" ::: "memory"); }

// stage one half-tile (16 KB = 2 issues x 512 lanes x 16B) of K-tile `ktile`.
// LDS dest linear; global source inverse-swizzled (T2 both-sides rule).
// Swizzle: 3-bit XOR, addr ^= ((row&7)<<4).
__device__ __forceinline__ void stage_unit(const char* __restrict__ tb, char* ldsRegion,
                                           int ktile, int half, int wid, int lane) {
#pragma unroll
  for (int issue = 0; issue < 2; ++issue) {
    const int d = half * 16384 + issue * 8192 + wid * 1024 + lane * 16;
    const int l = d ^ (((d >> 7) & 7) << 4);
    gload_lds16(tb + (size_t)(l >> 7) * 1024 + ktile * 128 + (l & 127),
                ldsRegion + half * 16384 + issue * 8192 + wid * 1024);
  }
}

// swizzled fragment read: logical (row R, k-bytes ks*64 + 16*g)
__device__ __forceinline__ bf16x8 rdfrag(const char* base, int R, int ks, int g) {
  return *(const bf16x8*)(base + R * 128 + ((ks * 64 + 16 * g) ^ ((R & 7) << 4)));
}

__device__ __forceinline__ void kgroup(int t, int smode, char* lds,
                                       const char* __restrict__ Ab,
                                       const char* __restrict__ Bb,
                                       int wr, int wc, int lane, int wid,
                                       f32x4 (&acc)[8][4]) {
  char* aL = lds + (t & 1) * 32768;
  char* bL = lds + 65536 + (t & 1) * 32768;
  char* aS = lds + ((t & 1) ^ 1) * 32768;
  char* bS = lds + 65536 + ((t & 1) ^ 1) * 32768;
  const int cg = lane & 15, g = lane >> 4;
  bf16x8 a[4][2], b0[2][2], b1[2][2];

  // ---- phase 1: read A01 + B01 of t; stage (t+1).A-half1
#pragma unroll
  for (int m = 0; m < 4; ++m)
#pragma unroll
    for (int ks = 0; ks < 2; ++ks)
      a[m][ks] = rdfrag(aL, wr * 128 + m * 16 + cg, ks, g);
#pragma unroll
  for (int n = 0; n < 2; ++n)
#pragma unroll
    for (int ks = 0; ks < 2; ++ks)
      b0[n][ks] = rdfrag(bL, wc * 64 + n * 16 + cg, ks, g);
  if (smode >= 1) stage_unit(Ab, aS, t + 1, 1, wid, lane);
  barf();
  __builtin_amdgcn_s_setprio(1);
#pragma unroll
  for (int m = 0; m < 4; ++m)
#pragma unroll
    for (int n = 0; n < 2; ++n)
#pragma unroll
      for (int ks = 0; ks < 2; ++ks)
        acc[m][n] = __builtin_amdgcn_mfma_f32_16x16x32_bf16(a[m][ks], b0[n][ks], acc[m][n], 0, 0, 0);
  __builtin_amdgcn_s_setprio(0);
  barf();

  // ---- phase 2: read B23 of t; stage (t+1).B-half0
#pragma unroll
  for (int n = 0; n < 2; ++n)
#pragma unroll
    for (int ks = 0; ks < 2; ++ks)
      b1[n][ks] = rdfrag(bL, wc * 64 + (n + 2) * 16 + cg, ks, g);
  if (smode >= 1) stage_unit(Bb, bS, t + 1, 0, wid, lane);
  barf();
  __builtin_amdgcn_s_setprio(1);
#pragma unroll
  for (int m = 0; m < 4; ++m)
#pragma unroll
    for (int n = 0; n < 2; ++n)
#pragma unroll
      for (int ks = 0; ks < 2; ++ks)
        acc[m][n + 2] = __builtin_amdgcn_mfma_f32_16x16x32_bf16(a[m][ks], b1[n][ks], acc[m][n + 2], 0, 0, 0);
  __builtin_amdgcn_s_setprio(0);
  barf();

  // ---- phase 3: read A23 of t (overwrite a); stage (t+1).B-half1
#pragma unroll
  for (int m = 0; m < 4; ++m)
#pragma unroll
    for (int ks = 0; ks < 2; ++ks)
      a[m][ks] = rdfrag(aL, wr * 128 + (m + 4) * 16 + cg, ks, g);
  if (smode >= 1) stage_unit(Bb, bS, t + 1, 1, wid, lane);
  barf();
  __builtin_amdgcn_s_setprio(1);
#pragma unroll
  for (int m = 0; m < 4; ++m)
#pragma unroll
    for (int n = 0; n < 2; ++n)
#pragma unroll
      for (int ks = 0; ks < 2; ++ks)
        acc[m + 4][n + 2] = __builtin_amdgcn_mfma_f32_16x16x32_bf16(a[m][ks], b1[n][ks], acc[m + 4][n + 2], 0, 0, 0);
  __builtin_amdgcn_s_setprio(0);
  barf();

  // ---- phase 4: MFMA A23 x B01 (regs only); stage (t+2).A-half0 into read-parity buf
  if (smode == 2) stage_unit(Ab, aL, t + 2, 0, wid, lane);  // safe: all t-reads retired by ph3
  barf();
  __builtin_amdgcn_s_setprio(1);
#pragma unroll
  for (int m = 0; m < 4; ++m)
#pragma unroll
    for (int n = 0; n < 2; ++n)
#pragma unroll
      for (int ks = 0; ks < 2; ++ks)
        acc[m + 4][n] = __builtin_amdgcn_mfma_f32_16x16x32_bf16(a[m][ks], b0[n][ks], acc[m + 4][n], 0, 0, 0);
  __builtin_amdgcn_s_setprio(0);
  if (smode == 2) vmcnt2();        // ledger: only (t+2).A0 (2 loads) may stay in flight
  else if (smode == 1) vmcnt0();   // tail: tile7 fully staged, nothing younger
  barf();
}

__global__ __launch_bounds__(512) void gemm8(const unsigned short* __restrict__ A,
                                             const unsigned short* __restrict__ B,
                                             const float* __restrict__ bias,
                                             float* __restrict__ C,
                                             float* __restrict__ pmaxT,
                                             float* __restrict__ psumT) {
  __shared__ char lds[131072];  // A dbuf 64K | B dbuf 64K ; reused as C retile [128][256] f32
  const int tid  = threadIdx.x;
  const int lane = tid & 63;
  const int wid  = tid >> 6;           // 8 waves: 2M x 4N
  const int wr   = wid >> 2, wc = wid & 3;

  // bijective XCD chunking over the 32x32 block grid (8x16 blocks per XCD)
  const int bid = blockIdx.x;
  const int xcd = bid & 7;
  const int s   = bid >> 3;
  const int by  = (xcd >> 1) * 8 + (s >> 4);
  const int bx  = (xcd & 1) * 16 + (s & 15);
  const int row0 = by * 256, col0 = bx * 256;

  const char* Ab = (const char*)A + (size_t)row0 * 1024;
  const char* Bb = (const char*)B + (size_t)col0 * 1024;

  f32x4 acc[8][4];

  // INSTRUMENTATION: repeat {zero-acc, prologue, K-loop} GREPS times; only the
  // last rep's acc feeds the epilogue (outputs identical; LDS overwrite safe
  // because all prior-rep ds_reads are register-retired before its last barrier).
#pragma unroll 1
  for (int rep = 0; rep < GREPS; ++rep) {
#pragma unroll
    for (int m = 0; m < 8; ++m)
#pragma unroll
      for (int n = 0; n < 4; ++n)
#pragma unroll
        for (int j = 0; j < 4; ++j)
          acc[m][n][j] = 0.f;

    // prologue: stage tile0 fully + tile1.A-half0; wait tile0 (2 younger in flight)
    stage_unit(Ab, lds, 0, 0, wid, lane);
    stage_unit(Ab, lds, 0, 1, wid, lane);
    stage_unit(Bb, lds + 65536, 0, 0, wid, lane);
    stage_unit(Bb, lds + 65536, 0, 1, wid, lane);
    stage_unit(Ab, lds + 32768, 1, 0, wid, lane);
    vmcnt2();
    barf();

    for (int t = 0; t < 6; ++t)
      kgroup(t, 2, lds, Ab, Bb, wr, wc, lane, wid, acc);
    kgroup(6, 1, lds, Ab, Bb, wr, wc, lane, wid, acc);
    kgroup(7, 0, lds, Ab, Bb, wr, wc, lane, wid, acc);
  }

  // ---- epilogue: LDS retile -> coalesced row stores + per-row {max,sumexp} ----
  // LDS rows rotated by -3 cols so the (base%4==1) global misalignment maps to
  // aligned LDS f32x4 reads: lds word (c+253)&255 holds col c.
  const int cg = lane & 15, g = lane >> 4;
  float bv[4];
#pragma unroll
  for (int n = 0; n < 4; ++n) bv[n] = bias[col0 + wc * 64 + n * 16 + cg];

  float* cl = (float*)lds;
  __syncthreads();
#pragma unroll
  for (int h = 0; h < 2; ++h) {
    if (wr == h) {
#pragma unroll
      for (int m = 0; m < 8; ++m)
#pragma unroll
        for (int n = 0; n < 4; ++n) {
          const int cw = ((wc * 64 + n * 16 + cg) + 253) & 255;
#pragma unroll
          for (int rr = 0; rr < 4; ++rr) {
            const int R = m * 16 + 4 * g + rr;   // local row 0..127
            cl[R * 256 + cw] = acc[m][n][rr] + bv[n];
          }
        }
    }
    __syncthreads();
    // each wave streams 16 rows: aligned f32x4 LDS read -> 1KB-contiguous store
    // (plain stores: logits/pmax/psum are re-read by row_finish -> keep L2/L3 warm)
#pragma unroll
    for (int k = 0; k < 16; ++k) {
      const int r = wid * 16 + k;
      const f32x4 v = *(const f32x4*)((char*)cl + r * 1024 + lane * 16);
      float vmx = fmaxf(fmaxf(v[0], v[1]), fmaxf(v[2], v[3]));
      float vsm = __expf(v[0]) + __expf(v[1]) + __expf(v[2]) + __expf(v[3]);
#pragma unroll
      for (int o = 1; o < 64; o <<= 1) {
        vmx = fmaxf(vmx, __shfl_xor(vmx, o));
        vsm += __shfl_xor(vsm, o);
      }
      const int grow = row0 + h * 128 + r;
      float* Crow = C + (size_t)grow * V_ + col0;
      if (lane < 63) {
        *((f32x4*)(Crow + 3) + lane) = v;  // cols 3+4l..+3
      } else {
        // lane63's f32x4 = cols {255, 0, 1, 2} (row rotation wrap)
        Crow[255] = v[0]; Crow[0] = v[1]; Crow[1] = v[2]; Crow[2] = v[3];
      }
      if (lane == 0) {
        pmaxT[(size_t)bx * BT_ + grow] = vmx;
        psumT[(size_t)bx * BT_ + grow] = vsm;
      }
    }
    __syncthreads();
  }
}

// ---- pass 2: per-row reduce partials, exact-fp32 argmax rescue, softmax sweep ----
__global__ __launch_bounds__(256) void row_finish(const float* __restrict__ logits,
                                                  const float* __restrict__ pmaxT,
                                                  const float* __restrict__ psumT,
                                                  const float* __restrict__ xf,
                                                  const float* __restrict__ wf,
                                                  const float* __restrict__ bias,
                                                  float* __restrict__ tokf,
                                                  float* __restrict__ soft) {
  const int row  = blockIdx.x;
  const int tid  = threadIdx.x;
  const int lane = tid & 63;
  const int wv   = tid >> 6;

  const int tl = lane & 31;                          // tile index (dup in high lanes)
  const float pm = pmaxT[(size_t)tl * BT_ + row];
  const float ps = psumT[(size_t)tl * BT_ + row];
  float m = pm, s = ps;
#pragma unroll
  for (int o = 1; o < 32; o <<= 1) {
    m = fmaxf(m, __shfl_xor(m, o));
    s += __shfl_xor(s, o);
  }
  const float si = 1.0f / s;

  const float* L = logits + (size_t)row * V_;
  float*       S = soft   + (size_t)row * V_;
  const f32x4* L4 = (const f32x4*)(L + 3);  // region base ==1 mod 4 -> +3 is 16B-aligned
  f32x4*       S4 = (f32x4*)(S + 3);

  if (wv == 0) {
    // ---- argmax rescue on wave 0 ----
    const float thr = m - TAU;
    unsigned long long tmask = __ballot(pm >= thr) & 0xFFFFFFFFull;
    float bestv = -1e30f;
    int   besti = 0x7fffffff;
    const float4* xr4 = (const float4*)(xf + (size_t)row * D_);
    while (tmask) {
      const int t = __ffsll(tmask) - 1;
      tmask &= tmask - 1;
      const float* Lr = L + t * 256;
#pragma unroll
      for (int kq = 0; kq < 4; ++kq) {
        const float lv = Lr[kq * 64 + lane];
        unsigned long long c = __ballot(lv >= thr);
        while (c) {
          const int j = __ffsll(c) - 1;
          c &= c - 1;
          const int col = t * 256 + kq * 64 + j;
          const float4* wr4 = (const float4*)(wf + (size_t)col * D_);
          float p = 0.f;
#pragma unroll
          for (int q = 0; q < 2; ++q) {
            const float4 av = xr4[lane + 64 * q];
            const float4 bvv = wr4[lane + 64 * q];
            p += av.x * bvv.x + av.y * bvv.y + av.z * bvv.z + av.w * bvv.w;
          }
#pragma unroll
          for (int o = 1; o < 64; o <<= 1) p += __shfl_xor(p, o);
          const float tot = p + bias[col];
          if (tot > bestv || (tot == bestv && col < besti)) { bestv = tot; besti = col; }
        }
      }
    }
    if (lane == 0) tokf[row] = (float)besti;
    // wave0's small static sweep share + head/tail
    if (lane < 3)  S[lane] = __expf(L[lane]) * si;
    if (lane == 3) S[8191] = __expf(L[8191]) * si;
#pragma unroll
    for (int k = 0; k < 2; ++k) {
      const int i = 1920 + k * 64 + lane;
      if (i < 2047) {
        const f32x4 v = L4[i];               // plain load (L3-resident after gemm)
        f32x4 o;
        o[0] = __expf(v[0]) * si; o[1] = __expf(v[1]) * si;
        o[2] = __expf(v[2]) * si; o[3] = __expf(v[3]) * si;
        __builtin_nontemporal_store(o, S4 + i);   // soft never re-read: nt ok
      }
    }
  } else {
    // waves 1-3: bulk sweep [0, 1920) immediately, no barrier
    const int t = tid - 64;  // 0..191
#pragma unroll
    for (int k = 0; k < 10; ++k) {
      const int i = k * 192 + t;
      const f32x4 v = L4[i];
      f32x4 o;
      o[0] = __expf(v[0]) * si; o[1] = __expf(v[1]) * si;
      o[2] = __expf(v[2]) * si; o[3] = __expf(v[3]) * si;
      __builtin_nontemporal_store(o, S4 + i);
    }
  }
}

// ---------------- pass 3: quantized gather + commitment loss ----------------
__global__ __launch_bounds__(256) void finalize_k(const float* __restrict__ tokf,
                                                  const float* __restrict__ cb,
                                                  const float* __restrict__ xf,
                                                  float* __restrict__ q,
                                                  float* __restrict__ loss) {
  const int row  = blockIdx.x * 4 + (threadIdx.x >> 6);
  const int lane = threadIdx.x & 63;
  const int idx  = (int)tokf[row];
  const f32x4* cr = (const f32x4*)(cb + (size_t)idx * D_);
  const f32x4* xr = (const f32x4*)(xf + (size_t)row * D_);
  f32x4* qr = (f32x4*)(q + (size_t)row * D_);
  float ls = 0.f;
#pragma unroll
  for (int j = 0; j < 2; ++j) {
    const int c = lane + j * 64;
    const f32x4 cv = cr[c];
    const f32x4 xv = xr[c];
    __builtin_nontemporal_store(cv, qr + c);   // q never re-read: nt ok
    const float dx = cv[0] - xv[0], dy = cv[1] - xv[1], dz = cv[2] - xv[2], dw = cv[3] - xv[3];
    ls += dx * dx + dy * dy + dz * dz + dw * dw;
  }
#pragma unroll
  for (int o = 32; o; o >>= 1) ls += __shfl_xor(ls, o);
  if (lane == 0) atomicAdd(loss, ls * (1.0f / 4194304.0f));
}

extern "C" void kernel_launch(void* const* d_in, const int* in_sizes, int n_in,
                              void* d_out, int out_size, void* d_ws, size_t ws_size,
                              hipStream_t stream) {
  const float* x  = (const float*)d_in[0];  // inputs   [8192][512]
  const float* cb = (const float*)d_in[1];  // codebook [8192][512]
  const float* wl = (const float*)d_in[2];  // W_logits [8192][512]
  const float* bl = (const float*)d_in[3];  // b_logits [8192]
  float* out = (float*)d_out;

  float* qout   = out + OFF_Q;
  float* tokf   = out + OFF_TOK;
  float* loss   = out + OFF_LOSS;
  float* soft   = out + OFF_SOFT;
  float* logits = out + OFF_LOGITS;

  // scratch carved from output regions (each rewritten later in the pipeline):
  unsigned short* Abf = (unsigned short*)(out + STAGE_F);  // in soft region
  unsigned short* Wbf = Abf + (size_t)BT_ * D_;
  float* pmaxT = qout;            // [32][8192] in quantized region (finalize overwrites last)
  float* psumT = qout + 262144;   // [32][8192]

  hipMemsetAsync(loss, 0, 4, stream);

  to_bf16_k<<<2048, 256, 0, stream>>>((const f32x4*)x, (const f32x4*)wl,
                                      (u16x4*)Abf, (u16x4*)Wbf);
  gemm8<<<1024, 512, 0, stream>>>(Abf, Wbf, bl, logits, pmaxT, psumT);
  row_finish<<<8192, 256, 0, stream>>>(logits, pmaxT, psumT, x, wl, bl, tokf, soft);
  finalize_k<<<2048, 256, 0, stream>>>(tokf, cb, x, qout, loss);
}

// Round 9
// 380.890 us; speedup vs baseline: 1.9807x; 1.9807x over previous
//
#include <hip/hip_runtime.h>
#include <hip/hip_bf16.h>

#define BT_ 8192   // B*T
#define D_  512
#define V_  8192

#define NCHUNK 4
#define CROWS  2048   // rows per chunk

// d_out float offsets (outputs concatenated in return order)
#define OFF_Q      0
#define OFF_TOK    4194304
#define OFF_LOSS   4202496
#define OFF_SOFT   4202497
#define OFF_LOGITS 71311361
// bf16 staging scratch at the TAIL of the soft region (soft rows 7168..8191):
// overwritten only by row_finish(chunk 3), which runs after the last gemm chunk.
#define STAGE_F    62922752   // 16B-aligned (%4==0), = OFF_SOFT-1+67108864-8388609 rounded

#define TAU  0.02f

typedef __attribute__((ext_vector_type(8))) short bf16x8;
typedef __attribute__((ext_vector_type(4))) float f32x4;
typedef __attribute__((ext_vector_type(4))) unsigned short u16x4;

__device__ __forceinline__ unsigned short bf16rne(float f) {
  unsigned int u = __float_as_uint(f);
  return (unsigned short)((u + 0x7fffu + ((u >> 16) & 1u)) >> 16);
}

// ---------------- pass 0: fp32 -> bf16 for X and W (block-uniform source) ----------------
__global__ __launch_bounds__(256) void to_bf16_k(const f32x4* __restrict__ x,
                                                 const f32x4* __restrict__ w,
                                                 u16x4* __restrict__ xa,
                                                 u16x4* __restrict__ wb) {
  const int n4 = (BT_ * D_) / 4;
  const int half = gridDim.x >> 1;
  const bool isw = blockIdx.x >= half;
  const f32x4* __restrict__ s = isw ? w : x;
  u16x4* __restrict__ d = isw ? wb : xa;
  const int b0 = isw ? blockIdx.x - half : blockIdx.x;
  for (int i = b0 * 256 + threadIdx.x; i < n4; i += half * 256) {
    const f32x4 v = s[i];
    u16x4 o;
    o[0] = bf16rne(v[0]); o[1] = bf16rne(v[1]);
    o[2] = bf16rne(v[2]); o[3] = bf16rne(v[3]);
    d[i] = o;
  }
}

// ---------------- pass 1: 256x256 8-phase bf16 MFMA GEMM + fused stats epilogue ----------------
__device__ __forceinline__ void gload_lds16(const void* g, void* l) {
  __builtin_amdgcn_global_load_lds((const __attribute__((address_space(1))) void*)g,
                                   (__attribute__((address_space(3))) void*)l,
                                   16, 0, 0);
}

__device__ __forceinline__ void barf() {
  __builtin_amdgcn_s_barrier();
  asm volatile("" ::: "memory");
}
__device__ __forceinline__ void vmcnt2() { asm volatile("s_waitcnt vmcnt(2)" ::: "memory"); }
__device__ __forceinline__ void vmcnt0() { asm volatile("s_waitcnt vmcnt(0)" ::: "memory"); }

// stage one half-tile (16 KB) of K-tile `ktile`; LDS dest linear, global source
// inverse-swizzled (T2 both-sides): addr ^= ((row&7)<<4).
__device__ __forceinline__ void stage_unit(const char* __restrict__ tb, char* ldsRegion,
                                           int ktile, int half, int wid, int lane) {
#pragma unroll
  for (int issue = 0; issue < 2; ++issue) {
    const int d = half * 16384 + issue * 8192 + wid * 1024 + lane * 16;
    const int l = d ^ (((d >> 7) & 7) << 4);
    gload_lds16(tb + (size_t)(l >> 7) * 1024 + ktile * 128 + (l & 127),
                ldsRegion + half * 16384 + issue * 8192 + wid * 1024);
  }
}

__device__ __forceinline__ bf16x8 rdfrag(const char* base, int R, int ks, int g) {
  return *(const bf16x8*)(base + R * 128 + ((ks * 64 + 16 * g) ^ ((R & 7) << 4)));
}

__device__ __forceinline__ void kgroup(int t, int smode, char* lds,
                                       const char* __restrict__ Ab,
                                       const char* __restrict__ Bb,
                                       int wr, int wc, int lane, int wid,
                                       f32x4 (&acc)[8][4]) {
  char* aL = lds + (t & 1) * 32768;
  char* bL = lds + 65536 + (t & 1) * 32768;
  char* aS = lds + ((t & 1) ^ 1) * 32768;
  char* bS = lds + 65536 + ((t & 1) ^ 1) * 32768;
  const int cg = lane & 15, g = lane >> 4;
  bf16x8 a[4][2], b0[2][2], b1[2][2];

  // ---- phase 1: read A01 + B01 of t; stage (t+1).A-half1
#pragma unroll
  for (int m = 0; m < 4; ++m)
#pragma unroll
    for (int ks = 0; ks < 2; ++ks)
      a[m][ks] = rdfrag(aL, wr * 128 + m * 16 + cg, ks, g);
#pragma unroll
  for (int n = 0; n < 2; ++n)
#pragma unroll
    for (int ks = 0; ks < 2; ++ks)
      b0[n][ks] = rdfrag(bL, wc * 64 + n * 16 + cg, ks, g);
  if (smode >= 1) stage_unit(Ab, aS, t + 1, 1, wid, lane);
  barf();
  __builtin_amdgcn_s_setprio(1);
#pragma unroll
  for (int m = 0; m < 4; ++m)
#pragma unroll
    for (int n = 0; n < 2; ++n)
#pragma unroll
      for (int ks = 0; ks < 2; ++ks)
        acc[m][n] = __builtin_amdgcn_mfma_f32_16x16x32_bf16(a[m][ks], b0[n][ks], acc[m][n], 0, 0, 0);
  __builtin_amdgcn_s_setprio(0);
  barf();

  // ---- phase 2: read B23 of t; stage (t+1).B-half0
#pragma unroll
  for (int n = 0; n < 2; ++n)
#pragma unroll
    for (int ks = 0; ks < 2; ++ks)
      b1[n][ks] = rdfrag(bL, wc * 64 + (n + 2) * 16 + cg, ks, g);
  if (smode >= 1) stage_unit(Bb, bS, t + 1, 0, wid, lane);
  barf();
  __builtin_amdgcn_s_setprio(1);
#pragma unroll
  for (int m = 0; m < 4; ++m)
#pragma unroll
    for (int n = 0; n < 2; ++n)
#pragma unroll
      for (int ks = 0; ks < 2; ++ks)
        acc[m][n + 2] = __builtin_amdgcn_mfma_f32_16x16x32_bf16(a[m][ks], b1[n][ks], acc[m][n + 2], 0, 0, 0);
  __builtin_amdgcn_s_setprio(0);
  barf();

  // ---- phase 3: read A23 of t; stage (t+1).B-half1
#pragma unroll
  for (int m = 0; m < 4; ++m)
#pragma unroll
    for (int ks = 0; ks < 2; ++ks)
      a[m][ks] = rdfrag(aL, wr * 128 + (m + 4) * 16 + cg, ks, g);
  if (smode >= 1) stage_unit(Bb, bS, t + 1, 1, wid, lane);
  barf();
  __builtin_amdgcn_s_setprio(1);
#pragma unroll
  for (int m = 0; m < 4; ++m)
#pragma unroll
    for (int n = 0; n < 2; ++n)
#pragma unroll
      for (int ks = 0; ks < 2; ++ks)
        acc[m + 4][n + 2] = __builtin_amdgcn_mfma_f32_16x16x32_bf16(a[m][ks], b1[n][ks], acc[m + 4][n + 2], 0, 0, 0);
  __builtin_amdgcn_s_setprio(0);
  barf();

  // ---- phase 4: MFMA A23 x B01; stage (t+2).A-half0 into read-parity buf
  if (smode == 2) stage_unit(Ab, aL, t + 2, 0, wid, lane);
  barf();
  __builtin_amdgcn_s_setprio(1);
#pragma unroll
  for (int m = 0; m < 4; ++m)
#pragma unroll
    for (int n = 0; n < 2; ++n)
#pragma unroll
      for (int ks = 0; ks < 2; ++ks)
        acc[m + 4][n] = __builtin_amdgcn_mfma_f32_16x16x32_bf16(a[m][ks], b0[n][ks], acc[m + 4][n], 0, 0, 0);
  __builtin_amdgcn_s_setprio(0);
  if (smode == 2) vmcnt2();
  else if (smode == 1) vmcnt0();
  barf();
}

// grid = 256 per chunk: by = bid&7 = XCD (all 32 CUs of an XCD share one A row-panel
// and jointly write contiguous 8MB logits row-panels), bx = bid>>3.
__global__ __launch_bounds__(512) void gemm8(const unsigned short* __restrict__ A,
                                             const unsigned short* __restrict__ B,
                                             const float* __restrict__ bias,
                                             float* __restrict__ C,
                                             float* __restrict__ pmaxT,
                                             float* __restrict__ psumT,
                                             int rowBase) {
  __shared__ char lds[131072];  // A dbuf 64K | B dbuf 64K ; reused as C retile
  const int tid  = threadIdx.x;
  const int lane = tid & 63;
  const int wid  = tid >> 6;           // 8 waves: 2M x 4N
  const int wr   = wid >> 2, wc = wid & 3;

  const int bid = blockIdx.x;
  const int by  = bid & 7;       // == XCD (round-robin dispatch)
  const int bx  = bid >> 3;      // 0..31 col-tile
  const int row0 = rowBase + by * 256;
  const int col0 = bx * 256;

  const char* Ab = (const char*)A + (size_t)row0 * (D_ * 2);
  const char* Bb = (const char*)B + (size_t)col0 * (D_ * 2);

  f32x4 acc[8][4] = {};

  // prologue: stage tile0 fully + tile1.A-half0
  stage_unit(Ab, lds, 0, 0, wid, lane);
  stage_unit(Ab, lds, 0, 1, wid, lane);
  stage_unit(Bb, lds + 65536, 0, 0, wid, lane);
  stage_unit(Bb, lds + 65536, 0, 1, wid, lane);
  stage_unit(Ab, lds + 32768, 1, 0, wid, lane);
  vmcnt2();
  barf();

  for (int t = 0; t < 6; ++t)
    kgroup(t, 2, lds, Ab, Bb, wr, wc, lane, wid, acc);
  kgroup(6, 1, lds, Ab, Bb, wr, wc, lane, wid, acc);
  kgroup(7, 0, lds, Ab, Bb, wr, wc, lane, wid, acc);

  // ---- epilogue: LDS retile -> 1KB-contiguous row stores + per-row {max,sumexp} ----
  // LDS rows rotated by -3 cols so the (base%4==1) global misalignment maps to
  // aligned LDS f32x4 reads.
  const int cg = lane & 15, g = lane >> 4;
  float bv[4];
#pragma unroll
  for (int n = 0; n < 4; ++n) bv[n] = bias[col0 + wc * 64 + n * 16 + cg];

  float* cl = (float*)lds;
  __syncthreads();
#pragma unroll
  for (int h = 0; h < 2; ++h) {
    if (wr == h) {
#pragma unroll
      for (int m = 0; m < 8; ++m)
#pragma unroll
        for (int n = 0; n < 4; ++n) {
          const int cw = ((wc * 64 + n * 16 + cg) + 253) & 255;
#pragma unroll
          for (int rr = 0; rr < 4; ++rr) {
            const int R = m * 16 + 4 * g + rr;
            cl[R * 256 + cw] = acc[m][n][rr] + bv[n];
          }
        }
    }
    __syncthreads();
#pragma unroll
    for (int k = 0; k < 16; ++k) {
      const int r = wid * 16 + k;
      const f32x4 v = *(const f32x4*)((char*)cl + r * 1024 + lane * 16);
      float vmx = fmaxf(fmaxf(v[0], v[1]), fmaxf(v[2], v[3]));
      float vsm = __expf(v[0]) + __expf(v[1]) + __expf(v[2]) + __expf(v[3]);
#pragma unroll
      for (int o = 1; o < 64; o <<= 1) {
        vmx = fmaxf(vmx, __shfl_xor(vmx, o));
        vsm += __shfl_xor(vsm, o);
      }
      const int grow = row0 + h * 128 + r;
      float* Crow = C + (size_t)grow * V_ + col0;
      if (lane < 63) {
        *((f32x4*)(Crow + 3) + lane) = v;
      } else {
        Crow[255] = v[0]; Crow[0] = v[1]; Crow[1] = v[2]; Crow[2] = v[3];
      }
      if (lane == 0) {
        pmaxT[(size_t)bx * BT_ + grow] = vmx;
        psumT[(size_t)bx * BT_ + grow] = vsm;
      }
    }
    __syncthreads();
  }
}

// ---- pass 2: per-row reduce partials, exact-fp32 argmax rescue, softmax sweep ----
__global__ __launch_bounds__(256) void row_finish(const float* __restrict__ logits,
                                                  const float* __restrict__ pmaxT,
                                                  const float* __restrict__ psumT,
                                                  const float* __restrict__ xf,
                                                  const float* __restrict__ wf,
                                                  const float* __restrict__ bias,
                                                  float* __restrict__ tokf,
                                                  float* __restrict__ soft,
                                                  int rowBase) {
  const int row  = rowBase + blockIdx.x;
  const int tid  = threadIdx.x;
  const int lane = tid & 63;
  const int wv   = tid >> 6;

  const int tl = lane & 31;
  const float pm = pmaxT[(size_t)tl * BT_ + row];
  const float ps = psumT[(size_t)tl * BT_ + row];
  float m = pm, s = ps;
#pragma unroll
  for (int o = 1; o < 32; o <<= 1) {
    m = fmaxf(m, __shfl_xor(m, o));
    s += __shfl_xor(s, o);
  }
  const float si = 1.0f / s;

  const float* L = logits + (size_t)row * V_;
  float*       S = soft   + (size_t)row * V_;
  const f32x4* L4 = (const f32x4*)(L + 3);
  f32x4*       S4 = (f32x4*)(S + 3);

  if (wv == 0) {
    // ---- argmax rescue on wave 0 ----
    const float thr = m - TAU;
    unsigned long long tmask = __ballot(pm >= thr) & 0xFFFFFFFFull;
    float bestv = -1e30f;
    int   besti = 0x7fffffff;
    const float4* xr4 = (const float4*)(xf + (size_t)row * D_);
    while (tmask) {
      const int t = __ffsll(tmask) - 1;
      tmask &= tmask - 1;
      const float* Lr = L + t * 256;
#pragma unroll
      for (int kq = 0; kq < 4; ++kq) {
        const float lv = Lr[kq * 64 + lane];
        unsigned long long c = __ballot(lv >= thr);
        while (c) {
          const int j = __ffsll(c) - 1;
          c &= c - 1;
          const int col = t * 256 + kq * 64 + j;
          const float4* wr4 = (const float4*)(wf + (size_t)col * D_);
          float p = 0.f;
#pragma unroll
          for (int q = 0; q < 2; ++q) {
            const float4 av = xr4[lane + 64 * q];
            const float4 bvv = wr4[lane + 64 * q];
            p += av.x * bvv.x + av.y * bvv.y + av.z * bvv.z + av.w * bvv.w;
          }
#pragma unroll
          for (int o = 1; o < 64; o <<= 1) p += __shfl_xor(p, o);
          const float tot = p + bias[col];
          if (tot > bestv || (tot == bestv && col < besti)) { bestv = tot; besti = col; }
        }
      }
    }
    if (lane == 0) tokf[row] = (float)besti;
    if (lane < 3)  S[lane] = __expf(L[lane]) * si;
    if (lane == 3) S[8191] = __expf(L[8191]) * si;
#pragma unroll
    for (int k = 0; k < 2; ++k) {
      const int i = 1920 + k * 64 + lane;
      if (i < 2047) {
        const f32x4 v = L4[i];               // plain load: L3-resident (chunked)
        f32x4 o;
        o[0] = __expf(v[0]) * si; o[1] = __expf(v[1]) * si;
        o[2] = __expf(v[2]) * si; o[3] = __expf(v[3]) * si;
        __builtin_nontemporal_store(o, S4 + i);   // soft never re-read
      }
    }
  } else {
    const int t = tid - 64;  // 0..191
#pragma unroll
    for (int k = 0; k < 10; ++k) {
      const int i = k * 192 + t;
      const f32x4 v = L4[i];
      f32x4 o;
      o[0] = __expf(v[0]) * si; o[1] = __expf(v[1]) * si;
      o[2] = __expf(v[2]) * si; o[3] = __expf(v[3]) * si;
      __builtin_nontemporal_store(o, S4 + i);
    }
  }
}

// ---------------- pass 3: quantized gather + commitment loss ----------------
__global__ __launch_bounds__(256) void finalize_k(const float* __restrict__ tokf,
                                                  const float* __restrict__ cb,
                                                  const float* __restrict__ xf,
                                                  float* __restrict__ q,
                                                  float* __restrict__ loss) {
  const int row  = blockIdx.x * 4 + (threadIdx.x >> 6);
  const int lane = threadIdx.x & 63;
  const int idx  = (int)tokf[row];
  const f32x4* cr = (const f32x4*)(cb + (size_t)idx * D_);
  const f32x4* xr = (const f32x4*)(xf + (size_t)row * D_);
  f32x4* qr = (f32x4*)(q + (size_t)row * D_);
  float ls = 0.f;
#pragma unroll
  for (int j = 0; j < 2; ++j) {
    const int c = lane + j * 64;
    const f32x4 cv = cr[c];
    const f32x4 xv = xr[c];
    __builtin_nontemporal_store(cv, qr + c);
    const float dx = cv[0] - xv[0], dy = cv[1] - xv[1], dz = cv[2] - xv[2], dw = cv[3] - xv[3];
    ls += dx * dx + dy * dy + dz * dz + dw * dw;
  }
#pragma unroll
  for (int o = 32; o; o >>= 1) ls += __shfl_xor(ls, o);
  if (lane == 0) atomicAdd(loss, ls * (1.0f / 4194304.0f));
}

extern "C" void kernel_launch(void* const* d_in, const int* in_sizes, int n_in,
                              void* d_out, int out_size, void* d_ws, size_t ws_size,
                              hipStream_t stream) {
  const float* x  = (const float*)d_in[0];  // inputs   [8192][512]
  const float* cb = (const float*)d_in[1];  // codebook [8192][512]
  const float* wl = (const float*)d_in[2];  // W_logits [8192][512]
  const float* bl = (const float*)d_in[3];  // b_logits [8192]
  float* out = (float*)d_out;

  float* qout   = out + OFF_Q;
  float* tokf   = out + OFF_TOK;
  float* loss   = out + OFF_LOSS;
  float* soft   = out + OFF_SOFT;
  float* logits = out + OFF_LOGITS;

  // scratch: bf16 staging at soft-region tail (rows 7168+, clobbered only by
  // row_finish chunk 3 which runs after the last gemm); partials in quantized
  // region (finalize overwrites last).
  unsigned short* Abf = (unsigned short*)(out + STAGE_F);
  unsigned short* Wbf = Abf + (size_t)BT_ * D_;
  float* pmaxT = qout;            // [32][8192]
  float* psumT = qout + 262144;   // [32][8192]

  hipMemsetAsync(loss, 0, 4, stream);

  to_bf16_k<<<2048, 256, 0, stream>>>((const f32x4*)x, (const f32x4*)wl,
                                      (u16x4*)Abf, (u16x4*)Wbf);
  for (int c = 0; c < NCHUNK; ++c) {
    gemm8<<<256, 512, 0, stream>>>(Abf, Wbf, bl, logits, pmaxT, psumT, c * CROWS);
    row_finish<<<CROWS, 256, 0, stream>>>(logits, pmaxT, psumT, x, wl, bl,
                                          tokf, soft, c * CROWS);
  }
  finalize_k<<<2048, 256, 0, stream>>>(tokf, cb, x, qout, loss);
}

// Round 10
// 335.200 us; speedup vs baseline: 2.2507x; 1.1363x over previous
//
#include <hip/hip_runtime.h>
#include <hip/hip_bf16.h>

#define BT_ 8192   // B*T
#define D_  512
#define V_  8192

// d_out float offsets (outputs concatenated in return order)
#define OFF_Q      0
#define OFF_TOK    4194304
#define OFF_LOSS   4202496
#define OFF_SOFT   4202497
#define OFF_LOGITS 71311361
// bf16 staging scratch at the TAIL of the soft region (soft rows >=7168):
// clobbered only by row_finish's soft writes, which run after all gemm reads.
#define STAGE_F    62922752

#define TAU  0.02f
#define EXP_NEG_TAU 0.98019867f   // exp(-0.02)
#define MAXC 64

typedef __attribute__((ext_vector_type(8))) short bf16x8;
typedef __attribute__((ext_vector_type(4))) float f32x4;
typedef __attribute__((ext_vector_type(4))) unsigned short u16x4;

__device__ __forceinline__ unsigned short bf16rne(float f) {
  unsigned int u = __float_as_uint(f);
  return (unsigned short)((u + 0x7fffu + ((u >> 16) & 1u)) >> 16);
}

// ---------------- pass 0: fp32 -> bf16 for X and W (block-uniform source) ----------------
__global__ __launch_bounds__(256) void to_bf16_k(const f32x4* __restrict__ x,
                                                 const f32x4* __restrict__ w,
                                                 u16x4* __restrict__ xa,
                                                 u16x4* __restrict__ wb) {
  const int n4 = (BT_ * D_) / 4;
  const int half = gridDim.x >> 1;
  const bool isw = blockIdx.x >= half;
  const f32x4* __restrict__ s = isw ? w : x;
  u16x4* __restrict__ d = isw ? wb : xa;
  const int b0 = isw ? blockIdx.x - half : blockIdx.x;
  for (int i = b0 * 256 + threadIdx.x; i < n4; i += half * 256) {
    const f32x4 v = s[i];
    u16x4 o;
    o[0] = bf16rne(v[0]); o[1] = bf16rne(v[1]);
    o[2] = bf16rne(v[2]); o[3] = bf16rne(v[3]);
    d[i] = o;
  }
}

// ---------------- pass 1: 256x256 8-phase bf16 MFMA GEMM (pure-store epilogue) ----------------
__device__ __forceinline__ void gload_lds16(const void* g, void* l) {
  __builtin_amdgcn_global_load_lds((const __attribute__((address_space(1))) void*)g,
                                   (__attribute__((address_space(3))) void*)l,
                                   16, 0, 0);
}

__device__ __forceinline__ void barf() {
  __builtin_amdgcn_s_barrier();
  asm volatile("" ::: "memory");
}
__device__ __forceinline__ void vmcnt2() { asm volatile("s_waitcnt vmcnt(2)" ::: "memory"); }
__device__ __forceinline__ void vmcnt0() { asm volatile("s_waitcnt vmcnt(0)" ::: "memory"); }

// stage one half-tile (16 KB) of K-tile `ktile`; LDS dest linear, global source
// inverse-swizzled (T2 both-sides): addr ^= ((row&7)<<4).
__device__ __forceinline__ void stage_unit(const char* __restrict__ tb, char* ldsRegion,
                                           int ktile, int half, int wid, int lane) {
#pragma unroll
  for (int issue = 0; issue < 2; ++issue) {
    const int d = half * 16384 + issue * 8192 + wid * 1024 + lane * 16;
    const int l = d ^ (((d >> 7) & 7) << 4);
    gload_lds16(tb + (size_t)(l >> 7) * 1024 + ktile * 128 + (l & 127),
                ldsRegion + half * 16384 + issue * 8192 + wid * 1024);
  }
}

__device__ __forceinline__ bf16x8 rdfrag(const char* base, int R, int ks, int g) {
  return *(const bf16x8*)(base + R * 128 + ((ks * 64 + 16 * g) ^ ((R & 7) << 4)));
}

__device__ __forceinline__ void kgroup(int t, int smode, char* lds,
                                       const char* __restrict__ Ab,
                                       const char* __restrict__ Bb,
                                       int wr, int wc, int lane, int wid,
                                       f32x4 (&acc)[8][4]) {
  char* aL = lds + (t & 1) * 32768;
  char* bL = lds + 65536 + (t & 1) * 32768;
  char* aS = lds + ((t & 1) ^ 1) * 32768;
  char* bS = lds + 65536 + ((t & 1) ^ 1) * 32768;
  const int cg = lane & 15, g = lane >> 4;
  bf16x8 a[4][2], b0[2][2], b1[2][2];

  // ---- phase 1: read A01 + B01 of t; stage (t+1).A-half1
#pragma unroll
  for (int m = 0; m < 4; ++m)
#pragma unroll
    for (int ks = 0; ks < 2; ++ks)
      a[m][ks] = rdfrag(aL, wr * 128 + m * 16 + cg, ks, g);
#pragma unroll
  for (int n = 0; n < 2; ++n)
#pragma unroll
    for (int ks = 0; ks < 2; ++ks)
      b0[n][ks] = rdfrag(bL, wc * 64 + n * 16 + cg, ks, g);
  if (smode >= 1) stage_unit(Ab, aS, t + 1, 1, wid, lane);
  barf();
  __builtin_amdgcn_s_setprio(1);
#pragma unroll
  for (int m = 0; m < 4; ++m)
#pragma unroll
    for (int n = 0; n < 2; ++n)
#pragma unroll
      for (int ks = 0; ks < 2; ++ks)
        acc[m][n] = __builtin_amdgcn_mfma_f32_16x16x32_bf16(a[m][ks], b0[n][ks], acc[m][n], 0, 0, 0);
  __builtin_amdgcn_s_setprio(0);
  barf();

  // ---- phase 2: read B23 of t; stage (t+1).B-half0
#pragma unroll
  for (int n = 0; n < 2; ++n)
#pragma unroll
    for (int ks = 0; ks < 2; ++ks)
      b1[n][ks] = rdfrag(bL, wc * 64 + (n + 2) * 16 + cg, ks, g);
  if (smode >= 1) stage_unit(Bb, bS, t + 1, 0, wid, lane);
  barf();
  __builtin_amdgcn_s_setprio(1);
#pragma unroll
  for (int m = 0; m < 4; ++m)
#pragma unroll
    for (int n = 0; n < 2; ++n)
#pragma unroll
      for (int ks = 0; ks < 2; ++ks)
        acc[m][n + 2] = __builtin_amdgcn_mfma_f32_16x16x32_bf16(a[m][ks], b1[n][ks], acc[m][n + 2], 0, 0, 0);
  __builtin_amdgcn_s_setprio(0);
  barf();

  // ---- phase 3: read A23 of t; stage (t+1).B-half1
#pragma unroll
  for (int m = 0; m < 4; ++m)
#pragma unroll
    for (int ks = 0; ks < 2; ++ks)
      a[m][ks] = rdfrag(aL, wr * 128 + (m + 4) * 16 + cg, ks, g);
  if (smode >= 1) stage_unit(Bb, bS, t + 1, 1, wid, lane);
  barf();
  __builtin_amdgcn_s_setprio(1);
#pragma unroll
  for (int m = 0; m < 4; ++m)
#pragma unroll
    for (int n = 0; n < 2; ++n)
#pragma unroll
      for (int ks = 0; ks < 2; ++ks)
        acc[m + 4][n + 2] = __builtin_amdgcn_mfma_f32_16x16x32_bf16(a[m][ks], b1[n][ks], acc[m + 4][n + 2], 0, 0, 0);
  __builtin_amdgcn_s_setprio(0);
  barf();

  // ---- phase 4: MFMA A23 x B01; stage (t+2).A-half0 into read-parity buf
  if (smode == 2) stage_unit(Ab, aL, t + 2, 0, wid, lane);
  barf();
  __builtin_amdgcn_s_setprio(1);
#pragma unroll
  for (int m = 0; m < 4; ++m)
#pragma unroll
    for (int n = 0; n < 2; ++n)
#pragma unroll
      for (int ks = 0; ks < 2; ++ks)
        acc[m + 4][n] = __builtin_amdgcn_mfma_f32_16x16x32_bf16(a[m][ks], b0[n][ks], acc[m + 4][n], 0, 0, 0);
  __builtin_amdgcn_s_setprio(0);
  if (smode == 2) vmcnt2();
  else if (smode == 1) vmcnt0();
  barf();
}

__global__ __launch_bounds__(512) void gemm8(const unsigned short* __restrict__ A,
                                             const unsigned short* __restrict__ B,
                                             const float* __restrict__ bias,
                                             float* __restrict__ C) {
  __shared__ char lds[131072];  // A dbuf 64K | B dbuf 64K ; reused as C retile
  const int tid  = threadIdx.x;
  const int lane = tid & 63;
  const int wid  = tid >> 6;           // 8 waves: 2M x 4N
  const int wr   = wid >> 2, wc = wid & 3;

  // bijective XCD chunking over the 32x32 block grid (8x16 blocks per XCD)
  const int bid = blockIdx.x;
  const int xcd = bid & 7;
  const int s   = bid >> 3;
  const int by  = (xcd >> 1) * 8 + (s >> 4);
  const int bx  = (xcd & 1) * 16 + (s & 15);
  const int row0 = by * 256, col0 = bx * 256;

  const char* Ab = (const char*)A + (size_t)row0 * (D_ * 2);
  const char* Bb = (const char*)B + (size_t)col0 * (D_ * 2);

  f32x4 acc[8][4] = {};

  // prologue: stage tile0 fully + tile1.A-half0
  stage_unit(Ab, lds, 0, 0, wid, lane);
  stage_unit(Ab, lds, 0, 1, wid, lane);
  stage_unit(Bb, lds + 65536, 0, 0, wid, lane);
  stage_unit(Bb, lds + 65536, 0, 1, wid, lane);
  stage_unit(Ab, lds + 32768, 1, 0, wid, lane);
  vmcnt2();
  barf();

  for (int t = 0; t < 6; ++t)
    kgroup(t, 2, lds, Ab, Bb, wr, wc, lane, wid, acc);
  kgroup(6, 1, lds, Ab, Bb, wr, wc, lane, wid, acc);
  kgroup(7, 0, lds, Ab, Bb, wr, wc, lane, wid, acc);

  // ---- epilogue: PURE retile + coalesced 1KB row stores (no stats, no exp, no shfl) ----
  // LDS rows rotated by -3 cols so the (base%4==1) global misalignment maps to
  // aligned LDS f32x4 reads: lds word (c+253)&255 holds col c.
  const int cg = lane & 15, g = lane >> 4;
  float bv[4];
#pragma unroll
  for (int n = 0; n < 4; ++n) bv[n] = bias[col0 + wc * 64 + n * 16 + cg];

  float* cl = (float*)lds;
  __syncthreads();
#pragma unroll
  for (int h = 0; h < 2; ++h) {
    if (wr == h) {
#pragma unroll
      for (int m = 0; m < 8; ++m)
#pragma unroll
        for (int n = 0; n < 4; ++n) {
          const int cw = ((wc * 64 + n * 16 + cg) + 253) & 255;
#pragma unroll
          for (int rr = 0; rr < 4; ++rr) {
            const int R = m * 16 + 4 * g + rr;
            cl[R * 256 + cw] = acc[m][n][rr] + bv[n];
          }
        }
    }
    __syncthreads();
#pragma unroll
    for (int k = 0; k < 16; ++k) {
      const int r = wid * 16 + k;
      const f32x4 v = *(const f32x4*)((char*)cl + r * 1024 + lane * 16);
      const int grow = row0 + h * 128 + r;
      float* Crow = C + (size_t)grow * V_ + col0;
      if (lane < 63) {
        *((f32x4*)(Crow + 3) + lane) = v;   // plain: row_finish re-reads soon
      } else {
        Crow[255] = v[0]; Crow[0] = v[1]; Crow[1] = v[2]; Crow[2] = v[3];
      }
    }
    __syncthreads();
  }
}

// ---- pass 2: single-pass row softmax + exact-fp32 argmax rescue (register-resident) ----
// 256 threads/row; thread t holds e=exp(logit) for L4[j*256+t], j=0..7 (32 floats).
// exp computed ONCE; stats block-reduced; soft written from registers.
__global__ __launch_bounds__(256) void row_finish(const float* __restrict__ logits,
                                                  const float* __restrict__ xf,
                                                  const float* __restrict__ wf,
                                                  const float* __restrict__ bias,
                                                  float* __restrict__ tokf,
                                                  float* __restrict__ soft) {
  const int row  = blockIdx.x;
  const int tid  = threadIdx.x;
  const int lane = tid & 63;
  const int wv   = tid >> 6;

  __shared__ float redM[4], redS[4];
  __shared__ int   cnum;
  __shared__ int   cidx[MAXC];

  const float* L = logits + (size_t)row * V_;
  float*       S = soft   + (size_t)row * V_;
  const f32x4* L4 = (const f32x4*)(L + 3);  // 16B-aligned; valid i in [0,2047)
  f32x4*       S4 = (f32x4*)(S + 3);

  // phase A: load + exp (once), per-thread max/sum
  f32x4 e[8];
  float m_e = 0.f, s = 0.f;   // all e > 0
#pragma unroll
  for (int j = 0; j < 8; ++j) {
    const int i = j * 256 + tid;
    if (i < 2047) {
      const f32x4 v = L4[i];
      f32x4 t;
      t[0] = __expf(v[0]); t[1] = __expf(v[1]);
      t[2] = __expf(v[2]); t[3] = __expf(v[3]);
      e[j] = t;
      m_e = fmaxf(m_e, fmaxf(fmaxf(t[0], t[1]), fmaxf(t[2], t[3])));
      s += t[0] + t[1] + t[2] + t[3];
    } else {
      e[j][0] = 0.f; e[j][1] = 0.f; e[j][2] = 0.f; e[j][3] = 0.f;
    }
  }
  // head (cols 0..2) + tail (col 8191) extras on threads 0..3
  float extra_e = 0.f;
  int   extra_col = -1;
  if (tid < 3)       extra_col = tid;
  else if (tid == 3) extra_col = 8191;
  if (extra_col >= 0) {
    extra_e = __expf(L[extra_col]);
    m_e = fmaxf(m_e, extra_e);
    s += extra_e;
  }
  // block reduce
#pragma unroll
  for (int o = 1; o < 64; o <<= 1) {
    m_e = fmaxf(m_e, __shfl_xor(m_e, o));
    s += __shfl_xor(s, o);
  }
  if (lane == 0) { redM[wv] = m_e; redS[wv] = s; }
  if (tid == 0) cnum = 0;
  __syncthreads();
  m_e = fmaxf(fmaxf(redM[0], redM[1]), fmaxf(redM[2], redM[3]));
  s   = redS[0] + redS[1] + redS[2] + redS[3];
  const float si    = 1.0f / s;
  const float thr_e = m_e * EXP_NEG_TAU;   // e >= thr_e  <=>  logit >= max - TAU

  // candidate collection (monotonic in e)
#pragma unroll
  for (int j = 0; j < 8; ++j) {
    const int i = j * 256 + tid;
#pragma unroll
    for (int q = 0; q < 4; ++q)
      if (e[j][q] >= thr_e) {
        const int p = atomicAdd(&cnum, 1);
        if (p < MAXC) cidx[p] = 3 + 4 * i + q;
      }
  }
  if (extra_col >= 0 && extra_e >= thr_e) {
    const int p = atomicAdd(&cnum, 1);
    if (p < MAXC) cidx[p] = extra_col;
  }
  __syncthreads();

  // wave 0: exact-fp32 rescue over candidates; waves 1-3 go straight to stores
  if (wv == 0) {
    const int cnt = min(cnum, MAXC);
    float bestv = -1e30f;
    int   besti = 0x7fffffff;
    const float4* xr4 = (const float4*)(xf + (size_t)row * D_);
    for (int c = 0; c < cnt; ++c) {
      const int col = cidx[c];
      const float4* wr4 = (const float4*)(wf + (size_t)col * D_);
      float p = 0.f;
#pragma unroll
      for (int q = 0; q < 2; ++q) {
        const float4 av = xr4[lane + 64 * q];
        const float4 bvv = wr4[lane + 64 * q];
        p += av.x * bvv.x + av.y * bvv.y + av.z * bvv.z + av.w * bvv.w;
      }
#pragma unroll
      for (int o = 1; o < 64; o <<= 1) p += __shfl_xor(p, o);
      const float tot = p + bias[col];
      if (tot > bestv || (tot == bestv && col < besti)) { bestv = tot; besti = col; }
    }
    if (lane == 0) tokf[row] = (float)besti;
  }

  // phase B: soft = e * si from registers (nt: never re-read)
#pragma unroll
  for (int j = 0; j < 8; ++j) {
    const int i = j * 256 + tid;
    if (i < 2047) {
      f32x4 o;
      o[0] = e[j][0] * si; o[1] = e[j][1] * si;
      o[2] = e[j][2] * si; o[3] = e[j][3] * si;
      __builtin_nontemporal_store(o, S4 + i);
    }
  }
  if (extra_col >= 0) S[extra_col] = extra_e * si;
}

// ---------------- pass 3: quantized gather + commitment loss ----------------
__global__ __launch_bounds__(256) void finalize_k(const float* __restrict__ tokf,
                                                  const float* __restrict__ cb,
                                                  const float* __restrict__ xf,
                                                  float* __restrict__ q,
                                                  float* __restrict__ loss) {
  const int row  = blockIdx.x * 4 + (threadIdx.x >> 6);
  const int lane = threadIdx.x & 63;
  const int idx  = (int)tokf[row];
  const f32x4* cr = (const f32x4*)(cb + (size_t)idx * D_);
  const f32x4* xr = (const f32x4*)(xf + (size_t)row * D_);
  f32x4* qr = (f32x4*)(q + (size_t)row * D_);
  float ls = 0.f;
#pragma unroll
  for (int j = 0; j < 2; ++j) {
    const int c = lane + j * 64;
    const f32x4 cv = cr[c];
    const f32x4 xv = xr[c];
    __builtin_nontemporal_store(cv, qr + c);
    const float dx = cv[0] - xv[0], dy = cv[1] - xv[1], dz = cv[2] - xv[2], dw = cv[3] - xv[3];
    ls += dx * dx + dy * dy + dz * dz + dw * dw;
  }
#pragma unroll
  for (int o = 32; o; o >>= 1) ls += __shfl_xor(ls, o);
  if (lane == 0) atomicAdd(loss, ls * (1.0f / 4194304.0f));
}

extern "C" void kernel_launch(void* const* d_in, const int* in_sizes, int n_in,
                              void* d_out, int out_size, void* d_ws, size_t ws_size,
                              hipStream_t stream) {
  const float* x  = (const float*)d_in[0];  // inputs   [8192][512]
  const float* cb = (const float*)d_in[1];  // codebook [8192][512]
  const float* wl = (const float*)d_in[2];  // W_logits [8192][512]
  const float* bl = (const float*)d_in[3];  // b_logits [8192]
  float* out = (float*)d_out;

  float* qout   = out + OFF_Q;
  float* tokf   = out + OFF_TOK;
  float* loss   = out + OFF_LOSS;
  float* soft   = out + OFF_SOFT;
  float* logits = out + OFF_LOGITS;

  // scratch: bf16 staging at soft-region tail (rows >=7168) — read only by gemm,
  // overwritten by row_finish's soft writes which run strictly after gemm.
  unsigned short* Abf = (unsigned short*)(out + STAGE_F);
  unsigned short* Wbf = Abf + (size_t)BT_ * D_;

  hipMemsetAsync(loss, 0, 4, stream);

  to_bf16_k<<<2048, 256, 0, stream>>>((const f32x4*)x, (const f32x4*)wl,
                                      (u16x4*)Abf, (u16x4*)Wbf);
  gemm8<<<1024, 512, 0, stream>>>(Abf, Wbf, bl, logits);
  row_finish<<<8192, 256, 0, stream>>>(logits, x, wl, bl, tokf, soft);
  finalize_k<<<2048, 256, 0, stream>>>(tokf, cb, x, qout, loss);
}